// Round 18
// baseline (27.015 us; speedup 1.0000x reference)
//
#include <hip/hip_runtime.h>
#include <hip/hip_bf16.h>
#include <math.h>

// R18: R13 revert (best: 24.1us) with ONE isolated change: regular stores
// instead of __builtin_nontemporal_store (nt entered R8 un-isolated).
// Regular stores let the 256MB L3 absorb the 32MB out-burst (fills prove
// >6.5 TB/s through that path); nt forces 64B-segment @256KB-stride writes
// straight to HBM. A/B vs R13's 24.1.
// Ledger: 9 structural schedules (R8-R17) all land 24-27us; this round
// finalizes the best structure with the last untested knob.

#define ALPHA_F 8.3f

constexpr int B_    = 4;
constexpr int CIN   = 32;
constexpr int COUT  = 32;
constexpr int H_    = 256;
constexpr int W_    = 256;
constexpr int KTAPS = 9;
constexpr int HW    = H_ * W_;

typedef __attribute__((ext_vector_type(8))) short bf16x8;
typedef __attribute__((ext_vector_type(4))) float f32x4;

static __device__ __forceinline__ short f2bf(float f) {
    __hip_bfloat16 h = __float2bfloat16(f);
    return __builtin_bit_cast(short, h);
}

// ---- prep: weights into per-lane A-fragment layout (verified R2-R17) ----
__global__ void prep_wfrag(const float* __restrict__ w, short* __restrict__ wf) {
    int idx = blockIdx.x * 256 + threadIdx.x;
    if (idx >= KTAPS * 2 * 64 * 8) return;
    int e  = idx & 7;
    int l  = (idx >> 3) & 63;
    int t  = (idx >> 9) & 1;
    int ij = idx >> 10;
    int o  = t * 16 + (l & 15);
    int c  = (l >> 4) * 8 + e;
    wf[idx] = f2bf(w[(o * CIN + c) * KTAPS + ij]);
}

// ---- fused main kernel: 4 rows x 64 px tile, single residency generation --
__global__ __launch_bounds__(256, 4)
void dconv_final(const float* __restrict__ x,
                 const float* __restrict__ depth,
                 const short* __restrict__ wf,
                 float* __restrict__ out) {
    __shared__ __align__(16) short xs[6][66][40];   // 31,680 B bf16 x tile
    __shared__ float dsh[6][66];                    //  1,584 B depth stencil

    // XCD-bijective swizzle: 1024 blocks, 1024 % 8 == 0
    const int bid  = (int)blockIdx.x;
    const int bswz = (bid & 7) * 128 + (bid >> 3);

    const int b    = bswz >> 8;          // image (4)
    const int hseg = (bswz >> 2) & 63;   // 64 row-groups
    const int wseg = (bswz & 3) << 6;    // 4 col segments of 64 px
    const int h0   = hseg << 2;          // first output row
    const int tid  = threadIdx.x;
    const int lane = tid & 63;
    const float* xb  = x + (size_t)b * CIN * HW;
    const float* dpl = depth + (size_t)b * HW;

    // ========== PHASE A: issue ALL x/depth loads (batched) ==========
    float xv0[24], xv1[24];
#pragma unroll
    for (int it = 0; it < 24; ++it) {
        const int idx = it * 256 + tid;
        const int q   = idx & 63;
        const int cp  = (idx >> 6) & 15;
        const int r   = idx >> 10;                   // 0..5
        const int row = h0 + r - 1;
        const int rowc = ((unsigned)row < (unsigned)H_) ? row : h0;  // clamp
        const size_t gb = (size_t)(2 * cp) * HW + rowc * W_ + wseg + q;
        xv0[it] = xb[gb];
        xv1[it] = xb[gb + HW];
    }
    float hv0, hv1;
    {
        const int side = tid & 1;
        const int hrc  = tid >> 1;                   // 0..95
        const int hcp  = hrc & 15;
        const int hr   = (hrc >> 4) % 6;             // 0..5
        const int hrow = h0 + hr - 1;
        const int hwx  = wseg - 1 + side * 65;
        const bool hok = (tid < 192) &&
                         ((unsigned)hrow < (unsigned)H_) &&
                         ((unsigned)hwx  < (unsigned)W_);
        const size_t gb = (size_t)(2 * hcp) * HW +
                          (hok ? (size_t)(hrow * W_ + hwx) : 0);
        hv0 = xb[gb];
        hv1 = xb[gb + HW];
    }
    float dv0, dv1;
    {
        const int r0   = tid / 66;                   // 0..3
        const int q0   = tid - r0 * 66;
        const int row0 = h0 + r0 - 1;
        const int wx0  = wseg - 1 + q0;
        const bool ok0 = ((unsigned)row0 < (unsigned)H_) &&
                         ((unsigned)wx0  < (unsigned)W_);
        dv0 = dpl[ok0 ? (row0 * W_ + wx0) : 0];

        const int k1   = tid + 256;
        const int r1   = (k1 / 66) % 6;
        const int q1   = k1 - (k1 / 66) * 66;
        const int row1 = h0 + r1 - 1;
        const int wx1  = wseg - 1 + q1;
        const bool ok1 = (k1 < 396) &&
                         ((unsigned)row1 < (unsigned)H_) &&
                         ((unsigned)wx1  < (unsigned)W_);
        dv1 = dpl[ok1 ? (row1 * W_ + wx1) : 0];
    }

    // ========== PHASE B: convert + LDS writes ==========
#pragma unroll
    for (int it = 0; it < 24; ++it) {
        const int idx = it * 256 + tid;
        const int q   = idx & 63;
        const int cp  = (idx >> 6) & 15;
        const int r   = idx >> 10;
        const bool ok = ((unsigned)(h0 + r - 1) < (unsigned)H_);
        const float f0 = ok ? xv0[it] : 0.f;
        const float f1 = ok ? xv1[it] : 0.f;
        const int v = (int)(unsigned short)f2bf(f0) |
                      ((int)(unsigned short)f2bf(f1) << 16);
        ((int*)&xs[r][q + 1][0])[cp] = v;
    }
    if (tid < 192) {
        const int side = tid & 1;
        const int hrc  = tid >> 1;
        const int hcp  = hrc & 15;
        const int hr   = hrc >> 4;                   // 0..5
        const int hrow = h0 + hr - 1;
        const int hwx  = wseg - 1 + side * 65;
        const bool hok = ((unsigned)hrow < (unsigned)H_) &&
                         ((unsigned)hwx  < (unsigned)W_);
        const float f0 = hok ? hv0 : 0.f;
        const float f1 = hok ? hv1 : 0.f;
        const int v = (int)(unsigned short)f2bf(f0) |
                      ((int)(unsigned short)f2bf(f1) << 16);
        ((int*)&xs[hr][side * 65][0])[hcp] = v;
    }
    {
        const int r0   = tid / 66;
        const int q0   = tid - r0 * 66;
        const bool ok0 = ((unsigned)(h0 + r0 - 1) < (unsigned)H_) &&
                         ((unsigned)(wseg - 1 + q0) < (unsigned)W_);
        dsh[r0][q0] = ok0 ? dv0 : 0.f;
        const int k1 = tid + 256;
        if (k1 < 396) {
            const int r1   = k1 / 66;
            const int q1   = k1 - r1 * 66;
            const bool ok1 = ((unsigned)(h0 + r1 - 1) < (unsigned)H_) &&
                             ((unsigned)(wseg - 1 + q1) < (unsigned)W_);
            dsh[r1][q1] = ok1 ? dv1 : 0.f;
        }
    }

    // wf A-fragments: issued AFTER staging regs die, drain overlaps barrier.
    const bf16x8* wfv = (const bf16x8*)wf;
    bf16x8 wa[2 * KTAPS];
#pragma unroll
    for (int k = 0; k < 2 * KTAPS; ++k) wa[k] = wfv[k * 64 + lane];

    __syncthreads();

    // ========== compute: wave w owns output row h0+w; 4 subtiles ==========
    const int w    = tid >> 6;           // 0..3
    const int n    = lane & 15;
    const int cg   = (lane >> 4) * 8;
    const int rl   = w + 1;              // local row in halo coords
    const int hrow = h0 + w;             // global output row
    const int orow = (lane >> 4) * 4;
    const f32x4 z = {0.f, 0.f, 0.f, 0.f};

#pragma unroll
    for (int sub = 0; sub < 4; ++sub) {
        const int pl = sub * 16 + n + 1;
        const int wp = wseg + sub * 16 + n;
        const float dc = dsh[rl][pl];

        float s[KTAPS];
#pragma unroll
        for (int ij = 0; ij < KTAPS; ++ij) {
            const int di = ij / 3 - 1;
            const int dj = ij % 3 - 1;
            const bool ok = ((unsigned)(hrow + di) < (unsigned)H_) &&
                            ((unsigned)(wp + dj) < (unsigned)W_);
            s[ij] = ok ? __expf(-ALPHA_F * fabsf(dc - dsh[rl + di][pl + dj])) : 0.f;
        }

        f32x4 acc0 = z, acc1 = z;
#pragma unroll
        for (int ij = 0; ij < KTAPS; ++ij) {
            const int di = ij / 3 - 1;
            const int dj = ij % 3 - 1;
            const bf16x8 bfrag = *(const bf16x8*)&xs[rl + di][pl + dj][cg];
            const f32x4 t0 = __builtin_amdgcn_mfma_f32_16x16x32_bf16(wa[ij * 2 + 0], bfrag, z, 0, 0, 0);
            const f32x4 t1 = __builtin_amdgcn_mfma_f32_16x16x32_bf16(wa[ij * 2 + 1], bfrag, z, 0, 0, 0);
#pragma unroll
            for (int j = 0; j < 4; ++j) {
                acc0[j] = fmaf(s[ij], t0[j], acc0[j]);
                acc1[j] = fmaf(s[ij], t1[j], acc1[j]);
            }
        }

        // regular stores (the single A/B change vs R13's nontemporal)
        float* ob = out + (size_t)b * COUT * HW + hrow * W_ + wp;
#pragma unroll
        for (int j = 0; j < 4; ++j) {
            ob[(size_t)(orow + j) * HW]      = acc0[j];
            ob[(size_t)(orow + j + 16) * HW] = acc1[j];
        }
    }
}

// ---------- fp32 fallback (R1 kernel) ----------
__global__ __launch_bounds__(256)
void dconv_fallback(const float* __restrict__ x,
                    const float* __restrict__ depth,
                    const float* __restrict__ wgt,
                    float* __restrict__ out) {
    const int w  = threadIdx.x;
    const int bh = blockIdx.x;
    const int b  = bh >> 8;
    const int h  = bh & 255;

    const float* dplane = depth + (size_t)b * HW;
    const float  dc     = dplane[h * W_ + w];

    float acc[COUT];
#pragma unroll
    for (int o = 0; o < COUT; ++o) acc[o] = 0.f;

    const float* xb = x + (size_t)b * CIN * HW;

    for (int i = 0; i < 3; ++i) {
        const int  hh  = h + i - 1;
        const bool okh = ((unsigned)hh < (unsigned)H_);
        for (int j = 0; j < 3; ++j) {
            const int  ww = w + j - 1;
            const bool ok = okh && ((unsigned)ww < (unsigned)W_);
            const int  ij = i * 3 + j;
            const float dpv = ok ? dplane[hh * W_ + ww] : 0.f;
            const float sv  = __expf(-ALPHA_F * fabsf(dc - dpv));
            const int base = hh * W_ + ww;
#pragma unroll
            for (int c = 0; c < CIN; ++c) {
                const float v = (ok ? xb[c * HW + base] : 0.f) * sv;
#pragma unroll
                for (int o = 0; o < COUT; ++o) {
                    acc[o] = fmaf(v, wgt[(o * CIN + c) * KTAPS + ij], acc[o]);
                }
            }
        }
    }

    float* ob = out + ((size_t)b * COUT * H_ + h) * W_ + w;
#pragma unroll
    for (int o = 0; o < COUT; ++o) ob[o * HW] = acc[o];
}

extern "C" void kernel_launch(void* const* d_in, const int* in_sizes, int n_in,
                              void* d_out, int out_size, void* d_ws, size_t ws_size,
                              hipStream_t stream) {
    const float* x     = (const float*)d_in[0];
    const float* depth = (const float*)d_in[1];
    const float* wgt   = (const float*)d_in[2];
    float*       out   = (float*)d_out;

    const size_t wf_bytes = (size_t)(KTAPS * 2 * 64 * 8) * sizeof(short); // 18 KB

    if (ws_size >= wf_bytes) {
        short* wf = (short*)d_ws;
        prep_wfrag<<<(KTAPS * 2 * 64 * 8 + 255) / 256, 256, 0, stream>>>(wgt, wf);
        dconv_final<<<1024, 256, 0, stream>>>(x, depth, wf, out);
    } else {
        dconv_fallback<<<B_ * H_, 256, 0, stream>>>(x, depth, wgt, out);
    }
}

// Round 19
// 24.171 us; speedup vs baseline: 1.1177x; 1.1177x over previous
//
#include <hip/hip_runtime.h>
#include <hip/hip_bf16.h>
#include <math.h>

// FINAL (R19 = R13 restore): best-measured variant of the session, 24.1us.
// Structure: fused LDS-staged bf16-MFMA kernel.
//   - tile = 4 output rows x 64 px (halo 6x66), 1024 blocks, XCD-bijective
//     swizzle; launch_bounds(256,4) -> all blocks co-resident (1 generation).
//   - Phase A: ALL x/depth loads issued batched (R8 lesson: single pipelined
//     vmcnt drain; never interleave load->use in staging).
//   - Phase B: convert to bf16 pairs + LDS writes; wa[18] A-frag hoist issued
//     after staging regs die (drain overlaps barrier).
//   - compute: wave w owns row h0+w; 4 subtiles x 9 taps; MFMA pair + 
//     per-lane scalar sim fmac (sim folded POST-MFMA, channel-independent).
//   - epilogue: strided NONTEMPORAL stores (R18 A/B: nt beats regular by 3us;
//     L3 write-allocate otherwise evicts x mid-kernel).
// A/B-refuted alternatives (kept out): dwordx4 staging (R9), 5 blk/CU (R10),
// 2-stage pipeline (R14), barrier-free waves (R15), direct-global (R16),
// rolling ring (R17), regular stores (R18).

#define ALPHA_F 8.3f

constexpr int B_    = 4;
constexpr int CIN   = 32;
constexpr int COUT  = 32;
constexpr int H_    = 256;
constexpr int W_    = 256;
constexpr int KTAPS = 9;
constexpr int HW    = H_ * W_;

typedef __attribute__((ext_vector_type(8))) short bf16x8;
typedef __attribute__((ext_vector_type(4))) float f32x4;

static __device__ __forceinline__ short f2bf(float f) {
    __hip_bfloat16 h = __float2bfloat16(f);
    return __builtin_bit_cast(short, h);
}

// ---- prep: weights into per-lane A-fragment layout (verified R2-R18) ----
// wf[((ij*2 + t)*64 + lane)*8 + e] = W[o = t*16 + (lane&15), c = (lane>>4)*8 + e, ij]
__global__ void prep_wfrag(const float* __restrict__ w, short* __restrict__ wf) {
    int idx = blockIdx.x * 256 + threadIdx.x;
    if (idx >= KTAPS * 2 * 64 * 8) return;
    int e  = idx & 7;
    int l  = (idx >> 3) & 63;
    int t  = (idx >> 9) & 1;
    int ij = idx >> 10;
    int o  = t * 16 + (l & 15);
    int c  = (l >> 4) * 8 + e;
    wf[idx] = f2bf(w[(o * CIN + c) * KTAPS + ij]);
}

// ---- fused main kernel: 4 rows x 64 px tile, single residency generation --
__global__ __launch_bounds__(256, 4)
void dconv_final(const float* __restrict__ x,
                 const float* __restrict__ depth,
                 const short* __restrict__ wf,
                 float* __restrict__ out) {
    __shared__ __align__(16) short xs[6][66][40];   // 31,680 B bf16 x tile
    __shared__ float dsh[6][66];                    //  1,584 B depth stencil

    // XCD-bijective swizzle: 1024 blocks, 1024 % 8 == 0
    const int bid  = (int)blockIdx.x;
    const int bswz = (bid & 7) * 128 + (bid >> 3);

    const int b    = bswz >> 8;          // image (4)
    const int hseg = (bswz >> 2) & 63;   // 64 row-groups
    const int wseg = (bswz & 3) << 6;    // 4 col segments of 64 px
    const int h0   = hseg << 2;          // first output row
    const int tid  = threadIdx.x;
    const int lane = tid & 63;
    const float* xb  = x + (size_t)b * CIN * HW;
    const float* dpl = depth + (size_t)b * HW;

    // ========== PHASE A: issue ALL x/depth loads (batched) ==========
    // x main: 6 rows x 16 ch-pairs x 64 px = 6144 pairs, 24/thread
    float xv0[24], xv1[24];
#pragma unroll
    for (int it = 0; it < 24; ++it) {
        const int idx = it * 256 + tid;
        const int q   = idx & 63;
        const int cp  = (idx >> 6) & 15;
        const int r   = idx >> 10;                   // 0..5
        const int row = h0 + r - 1;
        const int rowc = ((unsigned)row < (unsigned)H_) ? row : h0;  // clamp
        const size_t gb = (size_t)(2 * cp) * HW + rowc * W_ + wseg + q;
        xv0[it] = xb[gb];
        xv1[it] = xb[gb + HW];
    }
    // halo columns: 6 rows x 16 ch-pairs x 2 sides = 192 units (tid<192)
    float hv0, hv1;
    {
        const int side = tid & 1;
        const int hrc  = tid >> 1;                   // 0..95
        const int hcp  = hrc & 15;
        const int hr   = (hrc >> 4) % 6;             // 0..5
        const int hrow = h0 + hr - 1;
        const int hwx  = wseg - 1 + side * 65;
        const bool hok = (tid < 192) &&
                         ((unsigned)hrow < (unsigned)H_) &&
                         ((unsigned)hwx  < (unsigned)W_);
        const size_t gb = (size_t)(2 * hcp) * HW +
                          (hok ? (size_t)(hrow * W_ + hwx) : 0);
        hv0 = xb[gb];
        hv1 = xb[gb + HW];
    }
    // depth stencil: 6 x 66 = 396 values (k = tid, tid+256)
    float dv0, dv1;
    {
        const int r0   = tid / 66;                   // 0..3
        const int q0   = tid - r0 * 66;
        const int row0 = h0 + r0 - 1;
        const int wx0  = wseg - 1 + q0;
        const bool ok0 = ((unsigned)row0 < (unsigned)H_) &&
                         ((unsigned)wx0  < (unsigned)W_);
        dv0 = dpl[ok0 ? (row0 * W_ + wx0) : 0];

        const int k1   = tid + 256;
        const int r1   = (k1 / 66) % 6;
        const int q1   = k1 - (k1 / 66) * 66;
        const int row1 = h0 + r1 - 1;
        const int wx1  = wseg - 1 + q1;
        const bool ok1 = (k1 < 396) &&
                         ((unsigned)row1 < (unsigned)H_) &&
                         ((unsigned)wx1  < (unsigned)W_);
        dv1 = dpl[ok1 ? (row1 * W_ + wx1) : 0];
    }

    // ========== PHASE B: convert + LDS writes ==========
#pragma unroll
    for (int it = 0; it < 24; ++it) {
        const int idx = it * 256 + tid;
        const int q   = idx & 63;
        const int cp  = (idx >> 6) & 15;
        const int r   = idx >> 10;
        const bool ok = ((unsigned)(h0 + r - 1) < (unsigned)H_);
        const float f0 = ok ? xv0[it] : 0.f;
        const float f1 = ok ? xv1[it] : 0.f;
        const int v = (int)(unsigned short)f2bf(f0) |
                      ((int)(unsigned short)f2bf(f1) << 16);
        ((int*)&xs[r][q + 1][0])[cp] = v;
    }
    if (tid < 192) {
        const int side = tid & 1;
        const int hrc  = tid >> 1;
        const int hcp  = hrc & 15;
        const int hr   = hrc >> 4;                   // 0..5
        const int hrow = h0 + hr - 1;
        const int hwx  = wseg - 1 + side * 65;
        const bool hok = ((unsigned)hrow < (unsigned)H_) &&
                         ((unsigned)hwx  < (unsigned)W_);
        const float f0 = hok ? hv0 : 0.f;
        const float f1 = hok ? hv1 : 0.f;
        const int v = (int)(unsigned short)f2bf(f0) |
                      ((int)(unsigned short)f2bf(f1) << 16);
        ((int*)&xs[hr][side * 65][0])[hcp] = v;
    }
    {
        const int r0   = tid / 66;
        const int q0   = tid - r0 * 66;
        const bool ok0 = ((unsigned)(h0 + r0 - 1) < (unsigned)H_) &&
                         ((unsigned)(wseg - 1 + q0) < (unsigned)W_);
        dsh[r0][q0] = ok0 ? dv0 : 0.f;
        const int k1 = tid + 256;
        if (k1 < 396) {
            const int r1   = k1 / 66;
            const int q1   = k1 - r1 * 66;
            const bool ok1 = ((unsigned)(h0 + r1 - 1) < (unsigned)H_) &&
                             ((unsigned)(wseg - 1 + q1) < (unsigned)W_);
            dsh[r1][q1] = ok1 ? dv1 : 0.f;
        }
    }

    // wf A-fragments: issued AFTER staging regs die, drain overlaps barrier.
    const bf16x8* wfv = (const bf16x8*)wf;
    bf16x8 wa[2 * KTAPS];
#pragma unroll
    for (int k = 0; k < 2 * KTAPS; ++k) wa[k] = wfv[k * 64 + lane];

    __syncthreads();

    // ========== compute: wave w owns output row h0+w; 4 subtiles ==========
    const int w    = tid >> 6;           // 0..3
    const int n    = lane & 15;
    const int cg   = (lane >> 4) * 8;
    const int rl   = w + 1;              // local row in halo coords
    const int hrow = h0 + w;             // global output row
    const int orow = (lane >> 4) * 4;
    const f32x4 z = {0.f, 0.f, 0.f, 0.f};

#pragma unroll
    for (int sub = 0; sub < 4; ++sub) {
        const int pl = sub * 16 + n + 1;
        const int wp = wseg + sub * 16 + n;
        const float dc = dsh[rl][pl];

        float s[KTAPS];
#pragma unroll
        for (int ij = 0; ij < KTAPS; ++ij) {
            const int di = ij / 3 - 1;
            const int dj = ij % 3 - 1;
            const bool ok = ((unsigned)(hrow + di) < (unsigned)H_) &&
                            ((unsigned)(wp + dj) < (unsigned)W_);
            s[ij] = ok ? __expf(-ALPHA_F * fabsf(dc - dsh[rl + di][pl + dj])) : 0.f;
        }

        f32x4 acc0 = z, acc1 = z;
#pragma unroll
        for (int ij = 0; ij < KTAPS; ++ij) {
            const int di = ij / 3 - 1;
            const int dj = ij % 3 - 1;
            const bf16x8 bfrag = *(const bf16x8*)&xs[rl + di][pl + dj][cg];
            const f32x4 t0 = __builtin_amdgcn_mfma_f32_16x16x32_bf16(wa[ij * 2 + 0], bfrag, z, 0, 0, 0);
            const f32x4 t1 = __builtin_amdgcn_mfma_f32_16x16x32_bf16(wa[ij * 2 + 1], bfrag, z, 0, 0, 0);
#pragma unroll
            for (int j = 0; j < 4; ++j) {
                acc0[j] = fmaf(s[ij], t0[j], acc0[j]);
                acc1[j] = fmaf(s[ij], t1[j], acc1[j]);
            }
        }

        // nontemporal strided stores (R18 A/B: nt beats regular by ~3us)
        float* ob = out + (size_t)b * COUT * HW + hrow * W_ + wp;
#pragma unroll
        for (int j = 0; j < 4; ++j) {
            __builtin_nontemporal_store(acc0[j], ob + (size_t)(orow + j) * HW);
            __builtin_nontemporal_store(acc1[j], ob + (size_t)(orow + j + 16) * HW);
        }
    }
}

// ---------- fp32 fallback (R1 kernel) ----------
__global__ __launch_bounds__(256)
void dconv_fallback(const float* __restrict__ x,
                    const float* __restrict__ depth,
                    const float* __restrict__ wgt,
                    float* __restrict__ out) {
    const int w  = threadIdx.x;
    const int bh = blockIdx.x;
    const int b  = bh >> 8;
    const int h  = bh & 255;

    const float* dplane = depth + (size_t)b * HW;
    const float  dc     = dplane[h * W_ + w];

    float acc[COUT];
#pragma unroll
    for (int o = 0; o < COUT; ++o) acc[o] = 0.f;

    const float* xb = x + (size_t)b * CIN * HW;

    for (int i = 0; i < 3; ++i) {
        const int  hh  = h + i - 1;
        const bool okh = ((unsigned)hh < (unsigned)H_);
        for (int j = 0; j < 3; ++j) {
            const int  ww = w + j - 1;
            const bool ok = okh && ((unsigned)ww < (unsigned)W_);
            const int  ij = i * 3 + j;
            const float dpv = ok ? dplane[hh * W_ + ww] : 0.f;
            const float sv  = __expf(-ALPHA_F * fabsf(dc - dpv));
            const int base = hh * W_ + ww;
#pragma unroll
            for (int c = 0; c < CIN; ++c) {
                const float v = (ok ? xb[c * HW + base] : 0.f) * sv;
#pragma unroll
                for (int o = 0; o < COUT; ++o) {
                    acc[o] = fmaf(v, wgt[(o * CIN + c) * KTAPS + ij], acc[o]);
                }
            }
        }
    }

    float* ob = out + ((size_t)b * COUT * H_ + h) * W_ + w;
#pragma unroll
    for (int o = 0; o < COUT; ++o) ob[o * HW] = acc[o];
}

extern "C" void kernel_launch(void* const* d_in, const int* in_sizes, int n_in,
                              void* d_out, int out_size, void* d_ws, size_t ws_size,
                              hipStream_t stream) {
    const float* x     = (const float*)d_in[0];
    const float* depth = (const float*)d_in[1];
    const float* wgt   = (const float*)d_in[2];
    float*       out   = (float*)d_out;

    const size_t wf_bytes = (size_t)(KTAPS * 2 * 64 * 8) * sizeof(short); // 18 KB

    if (ws_size >= wf_bytes) {
        short* wf = (short*)d_ws;
        prep_wfrag<<<(KTAPS * 2 * 64 * 8 + 255) / 256, 256, 0, stream>>>(wgt, wf);
        dconv_final<<<1024, 256, 0, stream>>>(x, depth, wf, out);
    } else {
        dconv_fallback<<<B_ * H_, 256, 0, stream>>>(x, depth, wgt, out);
    }
}